// Round 4
// baseline (10540.907 us; speedup 1.0000x reference)
//
#include <hip/hip_runtime.h>
#include <math.h>

constexpr int kB = 256;
constexpr int kT = 200;
constexpr int kD = 512;
constexpr int kU = 1024;
constexpr int kG = 4096;   // 4*U

typedef short frag8 __attribute__((ext_vector_type(8)));     // 8 bf16 (4 VGPRs)
typedef float floatx4 __attribute__((ext_vector_type(4)));   // MFMA C/D frag
typedef unsigned short ushort_t;

__device__ __forceinline__ ushort_t f2bf(float f) {
    union { float f; unsigned int u; } v; v.f = f;
    unsigned int r = v.u + 0x7fffu + ((v.u >> 16) & 1u);   // RNE
    return (ushort_t)(r >> 16);
}
__device__ __forceinline__ float bf2f(ushort_t h) {
    union { unsigned int u; float f; } v; v.u = ((unsigned int)h) << 16;
    return v.f;
}

// ---------------------------------------------------------------------------
// Repack [W (K1 rows); Uw (K-K1 rows)] fp32 [*,4096] -> bf16 fragment order.
// Gate-interleaved columns: n_new = 4*j + g  <->  n_old = g*1024 + j.
// frag8 addr (units): ((nb*nkb + kb)*4 + ct)*64 + lane,  nb = 64-col block,
// ct = 16-col group, frag covers cols nb*64+ct*16..+16, k = kb*32..+32.
// (verified layout — R2/R3 passed with absmax 0.0)
// ---------------------------------------------------------------------------
__global__ __launch_bounds__(256)
void repack_weights(const float* __restrict__ W, const float* __restrict__ Uw,
                    int K1, int K, ushort_t* __restrict__ out)
{
    const int nkb = K >> 5;
    const int kb = blockIdx.x % nkb;
    const int nb = blockIdx.x / nkb;
    __shared__ ushort_t tile[2048];
    const int tid = threadIdx.x;
#pragma unroll
    for (int i = 0; i < 8; i++) {
        int idx  = tid + (i << 8);         // 0..2047
        int kl   = idx >> 6;               // 0..31
        int lcol = idx & 63;               // 0..63
        int g  = lcol >> 4;
        int jl = lcol & 15;
        int k  = (kb << 5) + kl;
        int n_old = (g << 10) + (nb << 4) + jl;
        float v = (k < K1) ? W[(long)k * kG + n_old]
                           : Uw[(long)(k - K1) * kG + n_old];
        int n_new_l = (jl << 2) + g;       // local packed column
        int ng = n_new_l >> 4, nl = n_new_l & 15;
        int quad = kl >> 3, e = kl & 7;
        tile[ng * 512 + (quad * 16 + nl) * 8 + e] = f2bf(v);
    }
    __syncthreads();
    long base = ((long)(nb * nkb + kb)) * 2048;
    *(frag8*)&out[base + tid * 8] = *(frag8*)&tile[tid * 8];
}

__global__ __launch_bounds__(256)
void repack_bias(const float* __restrict__ b1, const float* __restrict__ b2,
                 float* __restrict__ o1, float* __restrict__ o2)
{
    int n = blockIdx.x * blockDim.x + threadIdx.x;   // 0..4095
    int n_old = ((n & 3) << 10) + (n >> 2);
    o1[n] = b1[n_old];
    o2[n] = b2[n_old];
}

// ---------------------------------------------------------------------------
// One-time embedding gather + fp32->bf16: xbf[b*T+t][d].
// ---------------------------------------------------------------------------
__global__ __launch_bounds__(128)
void xgather(const int* __restrict__ tokens, const float* __restrict__ emb,
             ushort_t* __restrict__ xbf)
{
    int bt = blockIdx.x;
    int tok = tokens[bt];
    float4 v = *(const float4*)(emb + (long)tok * kD + threadIdx.x * 4);
    unsigned int lo = ((unsigned int)f2bf(v.y) << 16) | f2bf(v.x);
    unsigned int hi = ((unsigned int)f2bf(v.w) << 16) | f2bf(v.z);
    uint2 p; p.x = lo; p.y = hi;
    *(uint2*)(xbf + (long)bt * kD + threadIdx.x * 4) = p;
}

// ---------------------------------------------------------------------------
// Fused LSTM step core. Block = 128 threads = 2 waves stacked by rows.
// Block tile: 128 rows x 64 packed cols (= 16 j x 4 gates). Wave: 64x64.
// No LDS staging, no __syncthreads: A and B frags load straight from global
// (B is pre-packed lane-contiguous; A is bf16 row-major, frag = 16B/lane).
// Epilogue: per-wave LDS transpose (16 rows at a time), gates in fp32,
// c-state fp32 in-place, h out bf16.
// ---------------------------------------------------------------------------
template<int NKB, int K1BK>
__device__ __forceinline__ void step_core(
    const ushort_t* __restrict__ A1, long a1_rs, long a1_off,
    const ushort_t* __restrict__ A2,
    const ushort_t* __restrict__ Wp,
    const float4* __restrict__ biasP4,
    float* __restrict__ cSt, ushort_t* __restrict__ hOut,
    float* __restrict__ zsw)
{
    const int tid  = threadIdx.x;
    const int lane = tid & 63;
    const int nb   = blockIdx.x;                       // 0..63
    const int wrow = (blockIdx.y << 7) + ((tid >> 6) << 6);
    const int kq   = (lane >> 4) << 3;                 // k-offset within frag

    const ushort_t* a1p[4];
    const ushort_t* a2p[4];
#pragma unroll
    for (int mi = 0; mi < 4; mi++) {
        int r = wrow + (mi << 4) + (lane & 15);
        a1p[mi] = A1 + (long)r * a1_rs + a1_off + kq;
        a2p[mi] = A2 + (long)r * kU + kq;
    }
    const frag8* wbase = (const frag8*)Wp + (long)nb * (NKB * 256) + lane;

    floatx4 acc[4][4];
#pragma unroll
    for (int i = 0; i < 4; i++)
#pragma unroll
        for (int j = 0; j < 4; j++) acc[i][j] = (floatx4){0.f, 0.f, 0.f, 0.f};

#pragma unroll 2
    for (int kb = 0; kb < K1BK; kb++) {
        const frag8* wp = wbase + kb * 256;
        frag8 b0 = wp[0], b1 = wp[64], b2 = wp[128], b3 = wp[192];
        frag8 a0 = *(const frag8*)(a1p[0] + kb * 32);
        frag8 a1 = *(const frag8*)(a1p[1] + kb * 32);
        frag8 a2 = *(const frag8*)(a1p[2] + kb * 32);
        frag8 a3 = *(const frag8*)(a1p[3] + kb * 32);
        acc[0][0] = __builtin_amdgcn_mfma_f32_16x16x32_bf16(a0, b0, acc[0][0], 0, 0, 0);
        acc[0][1] = __builtin_amdgcn_mfma_f32_16x16x32_bf16(a0, b1, acc[0][1], 0, 0, 0);
        acc[0][2] = __builtin_amdgcn_mfma_f32_16x16x32_bf16(a0, b2, acc[0][2], 0, 0, 0);
        acc[0][3] = __builtin_amdgcn_mfma_f32_16x16x32_bf16(a0, b3, acc[0][3], 0, 0, 0);
        acc[1][0] = __builtin_amdgcn_mfma_f32_16x16x32_bf16(a1, b0, acc[1][0], 0, 0, 0);
        acc[1][1] = __builtin_amdgcn_mfma_f32_16x16x32_bf16(a1, b1, acc[1][1], 0, 0, 0);
        acc[1][2] = __builtin_amdgcn_mfma_f32_16x16x32_bf16(a1, b2, acc[1][2], 0, 0, 0);
        acc[1][3] = __builtin_amdgcn_mfma_f32_16x16x32_bf16(a1, b3, acc[1][3], 0, 0, 0);
        acc[2][0] = __builtin_amdgcn_mfma_f32_16x16x32_bf16(a2, b0, acc[2][0], 0, 0, 0);
        acc[2][1] = __builtin_amdgcn_mfma_f32_16x16x32_bf16(a2, b1, acc[2][1], 0, 0, 0);
        acc[2][2] = __builtin_amdgcn_mfma_f32_16x16x32_bf16(a2, b2, acc[2][2], 0, 0, 0);
        acc[2][3] = __builtin_amdgcn_mfma_f32_16x16x32_bf16(a2, b3, acc[2][3], 0, 0, 0);
        acc[3][0] = __builtin_amdgcn_mfma_f32_16x16x32_bf16(a3, b0, acc[3][0], 0, 0, 0);
        acc[3][1] = __builtin_amdgcn_mfma_f32_16x16x32_bf16(a3, b1, acc[3][1], 0, 0, 0);
        acc[3][2] = __builtin_amdgcn_mfma_f32_16x16x32_bf16(a3, b2, acc[3][2], 0, 0, 0);
        acc[3][3] = __builtin_amdgcn_mfma_f32_16x16x32_bf16(a3, b3, acc[3][3], 0, 0, 0);
    }
#pragma unroll 2
    for (int kb = K1BK; kb < NKB; kb++) {
        const frag8* wp = wbase + kb * 256;
        int ko = (kb - K1BK) * 32;
        frag8 b0 = wp[0], b1 = wp[64], b2 = wp[128], b3 = wp[192];
        frag8 a0 = *(const frag8*)(a2p[0] + ko);
        frag8 a1 = *(const frag8*)(a2p[1] + ko);
        frag8 a2 = *(const frag8*)(a2p[2] + ko);
        frag8 a3 = *(const frag8*)(a2p[3] + ko);
        acc[0][0] = __builtin_amdgcn_mfma_f32_16x16x32_bf16(a0, b0, acc[0][0], 0, 0, 0);
        acc[0][1] = __builtin_amdgcn_mfma_f32_16x16x32_bf16(a0, b1, acc[0][1], 0, 0, 0);
        acc[0][2] = __builtin_amdgcn_mfma_f32_16x16x32_bf16(a0, b2, acc[0][2], 0, 0, 0);
        acc[0][3] = __builtin_amdgcn_mfma_f32_16x16x32_bf16(a0, b3, acc[0][3], 0, 0, 0);
        acc[1][0] = __builtin_amdgcn_mfma_f32_16x16x32_bf16(a1, b0, acc[1][0], 0, 0, 0);
        acc[1][1] = __builtin_amdgcn_mfma_f32_16x16x32_bf16(a1, b1, acc[1][1], 0, 0, 0);
        acc[1][2] = __builtin_amdgcn_mfma_f32_16x16x32_bf16(a1, b2, acc[1][2], 0, 0, 0);
        acc[1][3] = __builtin_amdgcn_mfma_f32_16x16x32_bf16(a1, b3, acc[1][3], 0, 0, 0);
        acc[2][0] = __builtin_amdgcn_mfma_f32_16x16x32_bf16(a2, b0, acc[2][0], 0, 0, 0);
        acc[2][1] = __builtin_amdgcn_mfma_f32_16x16x32_bf16(a2, b1, acc[2][1], 0, 0, 0);
        acc[2][2] = __builtin_amdgcn_mfma_f32_16x16x32_bf16(a2, b2, acc[2][2], 0, 0, 0);
        acc[2][3] = __builtin_amdgcn_mfma_f32_16x16x32_bf16(a2, b3, acc[2][3], 0, 0, 0);
        acc[3][0] = __builtin_amdgcn_mfma_f32_16x16x32_bf16(a3, b0, acc[3][0], 0, 0, 0);
        acc[3][1] = __builtin_amdgcn_mfma_f32_16x16x32_bf16(a3, b1, acc[3][1], 0, 0, 0);
        acc[3][2] = __builtin_amdgcn_mfma_f32_16x16x32_bf16(a3, b2, acc[3][2], 0, 0, 0);
        acc[3][3] = __builtin_amdgcn_mfma_f32_16x16x32_bf16(a3, b3, acc[3][3], 0, 0, 0);
    }

    // Epilogue: per-wave, 16 rows at a time through LDS (intra-wave only,
    // no __syncthreads; DS ops within a wave are ordered).
    const int q = lane >> 4, c16 = lane & 15;
#pragma unroll 1
    for (int mi = 0; mi < 4; mi++) {
#pragma unroll
        for (int ct = 0; ct < 4; ct++)
#pragma unroll
            for (int r = 0; r < 4; r++)
                zsw[((q << 2) + r) * 68 + (ct << 4) + c16] = acc[mi][ct][r];
#pragma unroll
        for (int ii = 0; ii < 4; ii++) {
            int cell = lane + (ii << 6);
            int rowl = cell >> 4, jl = cell & 15;
            float4 z4 = *(float4*)&zsw[rowl * 68 + (jl << 2)];
            float4 bv = biasP4[(nb << 4) + jl];
            float zi = z4.x + bv.x, zf = z4.y + bv.y;
            float zg = z4.z + bv.z, zo = z4.w + bv.w;
            float ig = 1.f / (1.f + __expf(-zi));
            float fg = 1.f / (1.f + __expf(-zf));
            float og = 1.f / (1.f + __expf(-zo));
            float gg = 1.f - 2.f / (__expf(2.f * zg) + 1.f);   // tanh
            int m = wrow + (mi << 4) + rowl;
            long ci = (long)m * kU + (nb << 4) + jl;
            float cn = fg * cSt[ci] + ig * gg;
            float tc = 1.f - 2.f / (__expf(2.f * cn) + 1.f);   // tanh
            cSt[ci] = cn;
            hOut[ci] = f2bf(og * tc);
        }
    }
}

// grid (64, 2, 2): z=0 -> layer2 step t2, z=1 -> layer1 step t1=t2+1
__global__ __launch_bounds__(128)
void lstm_merged(int zmask,
    const ushort_t* h1_for2, const ushort_t* h2prev, const ushort_t* W2p,
    const float* b2p, float* c2, ushort_t* h2out,
    const ushort_t* xbf, int t1,
    const ushort_t* h1prev, const ushort_t* W1p,
    const float* b1p, float* c1, ushort_t* h1out)
{
    __shared__ __align__(16) float zs[2][16 * 68];
    float* zsw = zs[threadIdx.x >> 6];
    if (blockIdx.z == 0) {
        if (!(zmask & 1)) return;
        step_core<64, 32>(h1_for2, kU, 0, h2prev, W2p,
                          (const float4*)b2p, c2, h2out, zsw);
    } else {
        if (!(zmask & 2)) return;
        step_core<48, 16>(xbf, (long)kT * kD, (long)t1 * kD, h1prev, W1p,
                          (const float4*)b1p, c1, h1out, zsw);
    }
}

// out[b] = sigmoid(h[b,:] . Wfc + bfc), h in bf16
__global__ __launch_bounds__(256)
void fc_sigmoid(const ushort_t* __restrict__ h, const float* __restrict__ Wfc,
                const float* __restrict__ bfc, float* __restrict__ out)
{
    int b = blockIdx.x, tid = threadIdx.x;
    float s = 0.f;
    for (int j = tid; j < kU; j += 256) s += bf2f(h[(long)b * kU + j]) * Wfc[j];
    __shared__ float red[4];
    for (int off = 32; off > 0; off >>= 1) s += __shfl_down(s, off, 64);
    if ((tid & 63) == 0) red[tid >> 6] = s;
    __syncthreads();
    if (tid == 0) {
        float t = red[0] + red[1] + red[2] + red[3] + bfc[0];
        out[b] = 1.f / (1.f + expf(-t));
    }
}

extern "C" void kernel_launch(void* const* d_in, const int* in_sizes, int n_in,
                              void* d_out, int out_size, void* d_ws, size_t ws_size,
                              hipStream_t stream)
{
    (void)in_sizes; (void)n_in; (void)out_size; (void)ws_size;

    const int*   tokens = (const int*)d_in[0];
    const float* emb    = (const float*)d_in[1];
    const float* W1     = (const float*)d_in[2];
    const float* U1     = (const float*)d_in[3];
    const float* b1     = (const float*)d_in[4];
    const float* W2     = (const float*)d_in[5];
    const float* U2     = (const float*)d_in[6];
    const float* b2     = (const float*)d_in[7];
    const float* Wfc    = (const float*)d_in[8];
    const float* bfc    = (const float*)d_in[9];
    float* out = (float*)d_out;

    // Workspace: ~86 MB (ws is ~410 MB per harness fill size)
    ushort_t* W1p = (ushort_t*)d_ws;                       // [1536*4096] bf16
    ushort_t* W2p = W1p + (size_t)1536 * kG;               // [2048*4096] bf16
    float* b1p = (float*)(W2p + (size_t)2048 * kG);        // [4096] f32
    float* b2p = b1p + kG;                                 // [4096] f32
    float* c1  = b2p + kG;                                 // [256*1024] f32
    float* c2  = c1 + (size_t)kB * kU;
    ushort_t* hbuf = (ushort_t*)(c2 + (size_t)kB * kU);    // 4 x [256*1024] bf16
    ushort_t* h1b[2] = { hbuf, hbuf + (size_t)kB * kU };
    ushort_t* h2b[2] = { hbuf + 2 * (size_t)kB * kU, hbuf + 3 * (size_t)kB * kU };
    ushort_t* xbf = hbuf + 4 * (size_t)kB * kU;            // [B*T*512] bf16

    repack_weights<<<48 * 64, 256, 0, stream>>>(W1, U1, 512, 1536, W1p);
    repack_weights<<<64 * 64, 256, 0, stream>>>(W2, U2, 1024, 2048, W2p);
    repack_bias<<<16, 256, 0, stream>>>(b1, b2, b1p, b2p);
    xgather<<<kB * kT, 128, 0, stream>>>(tokens, emb, xbf);
    // zero c1,c2 (fp32) + all h buffers (bf16): contiguous 4 MB
    hipMemsetAsync(c1, 0, (size_t)kB * kU * (2 * 4 + 4 * 2), stream);

    for (int l = 0; l <= kT; l++) {
        int t2 = l - 1, t1 = l;
        int zmask = (t2 >= 0 ? 1 : 0) | (t1 < kT ? 2 : 0);
        lstm_merged<<<dim3(64, 2, 2), 128, 0, stream>>>(zmask,
            h1b[(t2 + 1) & 1], h2b[t2 & 1], W2p, b2p, c2, h2b[(t2 + 1) & 1],
            xbf, t1, h1b[t1 & 1], W1p, b1p, c1, h1b[(t1 + 1) & 1]);
    }

    fc_sigmoid<<<kB, 256, 0, stream>>>(h2b[0], Wfc, bfc, out);
}

// Round 5
// 5856.958 us; speedup vs baseline: 1.7997x; 1.7997x over previous
//
#include <hip/hip_runtime.h>
#include <math.h>

constexpr int kB = 256;
constexpr int kT = 200;
constexpr int kD = 512;
constexpr int kU = 1024;
constexpr int kG = 4096;   // 4*U

typedef short frag8 __attribute__((ext_vector_type(8)));     // 8 bf16 (4 VGPRs)
typedef float floatx4 __attribute__((ext_vector_type(4)));   // MFMA C/D frag
typedef unsigned short ushort_t;

__device__ __forceinline__ ushort_t f2bf(float f) {
    union { float f; unsigned int u; } v; v.f = f;
    unsigned int r = v.u + 0x7fffu + ((v.u >> 16) & 1u);   // RNE
    return (ushort_t)(r >> 16);
}
__device__ __forceinline__ float bf2f(ushort_t h) {
    union { unsigned int u; float f; } v; v.u = ((unsigned int)h) << 16;
    return v.f;
}

// ---------------------------------------------------------------------------
// Repack [W (K1 rows); Uw (K-K1 rows)] fp32 [*,4096] -> bf16 fragment order.
// Gate-interleaved columns: n_new = 4*j + g  <->  n_old = g*1024 + j.
// frag8 addr (units): ((nb*nkb + kb)*4 + ct)*64 + lane  (verified, absmax 0.0)
// ---------------------------------------------------------------------------
__global__ __launch_bounds__(256)
void repack_weights(const float* __restrict__ W, const float* __restrict__ Uw,
                    int K1, int K, ushort_t* __restrict__ out)
{
    const int nkb = K >> 5;
    const int kb = blockIdx.x % nkb;
    const int nb = blockIdx.x / nkb;
    __shared__ ushort_t tile[2048];
    const int tid = threadIdx.x;
#pragma unroll
    for (int i = 0; i < 8; i++) {
        int idx  = tid + (i << 8);         // 0..2047
        int kl   = idx >> 6;               // 0..31
        int lcol = idx & 63;               // 0..63
        int g  = lcol >> 4;
        int jl = lcol & 15;
        int k  = (kb << 5) + kl;
        int n_old = (g << 10) + (nb << 4) + jl;
        float v = (k < K1) ? W[(long)k * kG + n_old]
                           : Uw[(long)(k - K1) * kG + n_old];
        int n_new_l = (jl << 2) + g;       // local packed column
        int ng = n_new_l >> 4, nl = n_new_l & 15;
        int quad = kl >> 3, e = kl & 7;
        tile[ng * 512 + (quad * 16 + nl) * 8 + e] = f2bf(v);
    }
    __syncthreads();
    long base = ((long)(nb * nkb + kb)) * 2048;
    *(frag8*)&out[base + tid * 8] = *(frag8*)&tile[tid * 8];
}

__global__ __launch_bounds__(256)
void repack_bias(const float* __restrict__ b1, const float* __restrict__ b2,
                 float* __restrict__ o1, float* __restrict__ o2)
{
    int n = blockIdx.x * blockDim.x + threadIdx.x;   // 0..4095
    int n_old = ((n & 3) << 10) + (n >> 2);
    o1[n] = b1[n_old];
    o2[n] = b2[n_old];
}

// One-time embedding gather + fp32->bf16: xbf[b*T+t][d].
__global__ __launch_bounds__(128)
void xgather(const int* __restrict__ tokens, const float* __restrict__ emb,
             ushort_t* __restrict__ xbf)
{
    int bt = blockIdx.x;
    int tok = tokens[bt];
    float4 v = *(const float4*)(emb + (long)tok * kD + threadIdx.x * 4);
    unsigned int lo = ((unsigned int)f2bf(v.y) << 16) | f2bf(v.x);
    unsigned int hi = ((unsigned int)f2bf(v.w) << 16) | f2bf(v.z);
    uint2 p; p.x = lo; p.y = hi;
    *(uint2*)(xbf + (long)bt * kD + threadIdx.x * 4) = p;
}

// ---------------------------------------------------------------------------
// Software-pipelined step core. Block = 256 thr = 4 waves (2 row x 2 col).
// Block tile 64 rows x 128 packed cols; wave tile 32x64 (2x4 frags, 8 MFMA/kb).
// K-loop processes batches of 4 kb (128 k), double-buffered in registers:
// load batch n+1, then MFMA batch n -> ~1 batch of latency always in flight.
// ---------------------------------------------------------------------------
struct Batch { frag8 A[8]; frag8 B[16]; };

template<int K1BK>
__device__ __forceinline__ void load_batch(int b, Batch& bb,
    const ushort_t* a1p0, const ushort_t* a1p1,
    const ushort_t* a2p0, const ushort_t* a2p1,
    const frag8* wbase)
{
    const int kb0 = b * 4;
    if (kb0 < K1BK) {
#pragma unroll
        for (int u = 0; u < 4; u++) {
            const frag8* wp = wbase + (kb0 + u) * 256;
            bb.B[u*4+0] = wp[0];   bb.B[u*4+1] = wp[64];
            bb.B[u*4+2] = wp[128]; bb.B[u*4+3] = wp[192];
            bb.A[u*2+0] = *(const frag8*)(a1p0 + (kb0 + u) * 32);
            bb.A[u*2+1] = *(const frag8*)(a1p1 + (kb0 + u) * 32);
        }
    } else {
#pragma unroll
        for (int u = 0; u < 4; u++) {
            const frag8* wp = wbase + (kb0 + u) * 256;
            bb.B[u*4+0] = wp[0];   bb.B[u*4+1] = wp[64];
            bb.B[u*4+2] = wp[128]; bb.B[u*4+3] = wp[192];
            bb.A[u*2+0] = *(const frag8*)(a2p0 + (kb0 - K1BK + u) * 32);
            bb.A[u*2+1] = *(const frag8*)(a2p1 + (kb0 - K1BK + u) * 32);
        }
    }
}

__device__ __forceinline__ void mfma_batch(const Batch& bb, floatx4 acc[2][4])
{
#pragma unroll
    for (int u = 0; u < 4; u++)
#pragma unroll
        for (int mi = 0; mi < 2; mi++)
#pragma unroll
            for (int ct = 0; ct < 4; ct++)
                acc[mi][ct] = __builtin_amdgcn_mfma_f32_16x16x32_bf16(
                    bb.A[u*2+mi], bb.B[u*4+ct], acc[mi][ct], 0, 0, 0);
}

template<int NKB, int K1BK>
__device__ __forceinline__ void step_core(
    const ushort_t* __restrict__ A1, long a1_rs, long a1_off,
    const ushort_t* __restrict__ A2,
    const ushort_t* __restrict__ Wp,
    const float4* __restrict__ biasP4,
    float* __restrict__ cSt, ushort_t* __restrict__ hOut,
    float* __restrict__ zsw)
{
    const int tid  = threadIdx.x;
    const int lane = tid & 63;
    const int wave = tid >> 6;
    const int nb2  = blockIdx.x * 2 + (wave & 1);        // 64-col superblock 0..63
    const int wrow = (blockIdx.y << 6) + ((wave >> 1) << 5);
    const int kq   = (lane >> 4) << 3;

    const int r0 = wrow + (lane & 15);
    const ushort_t* a1p0 = A1 + (long)r0 * a1_rs + a1_off + kq;
    const ushort_t* a1p1 = A1 + (long)(r0 + 16) * a1_rs + a1_off + kq;
    const ushort_t* a2p0 = A2 + (long)r0 * kU + kq;
    const ushort_t* a2p1 = A2 + (long)(r0 + 16) * kU + kq;
    const frag8* wbase = (const frag8*)Wp + (long)nb2 * (NKB * 256) + lane;

    floatx4 acc[2][4];
#pragma unroll
    for (int i = 0; i < 2; i++)
#pragma unroll
        for (int j = 0; j < 4; j++) acc[i][j] = (floatx4){0.f, 0.f, 0.f, 0.f};

    constexpr int NBATCH = NKB / 4;   // 12 (layer1) or 16 (layer2) — even
    Batch X, Y;
    load_batch<K1BK>(0, X, a1p0, a1p1, a2p0, a2p1, wbase);
#pragma unroll 1
    for (int b = 0; b < NBATCH; b += 2) {
        load_batch<K1BK>(b + 1, Y, a1p0, a1p1, a2p0, a2p1, wbase);
        mfma_batch(X, acc);
        if (b + 2 < NBATCH)
            load_batch<K1BK>(b + 2, X, a1p0, a1p1, a2p0, a2p1, wbase);
        mfma_batch(Y, acc);
    }

    // Epilogue: per-wave LDS transpose (intra-wave DS ordering), gates fp32.
    const int q = lane >> 4, c16 = lane & 15;
#pragma unroll 1
    for (int mi = 0; mi < 2; mi++) {
#pragma unroll
        for (int ct = 0; ct < 4; ct++)
#pragma unroll
            for (int r = 0; r < 4; r++)
                zsw[((q << 2) + r) * 68 + (ct << 4) + c16] = acc[mi][ct][r];
#pragma unroll
        for (int ii = 0; ii < 4; ii++) {
            int cell = lane + (ii << 6);
            int rowl = cell >> 4, jl = cell & 15;
            float4 z4 = *(float4*)&zsw[rowl * 68 + (jl << 2)];
            float4 bv = biasP4[(nb2 << 4) + jl];
            float zi = z4.x + bv.x, zf = z4.y + bv.y;
            float zg = z4.z + bv.z, zo = z4.w + bv.w;
            float ig = 1.f / (1.f + __expf(-zi));
            float fg = 1.f / (1.f + __expf(-zf));
            float og = 1.f / (1.f + __expf(-zo));
            float gg = 1.f - 2.f / (__expf(2.f * zg) + 1.f);   // tanh
            int m = wrow + (mi << 4) + rowl;
            long ci = (long)m * kU + (nb2 << 4) + jl;
            float cn = fg * cSt[ci] + ig * gg;
            float tc = 1.f - 2.f / (__expf(2.f * cn) + 1.f);   // tanh
            cSt[ci] = cn;
            hOut[ci] = f2bf(og * tc);
        }
    }
}

// grid (32, 4, 2): z=0 -> layer2 step t2, z=1 -> layer1 step t1=t2+1
__global__ __launch_bounds__(256, 1)
void lstm_merged(int zmask,
    const ushort_t* h1_for2, const ushort_t* h2prev, const ushort_t* W2p,
    const float* b2p, float* c2, ushort_t* h2out,
    const ushort_t* xbf, int t1,
    const ushort_t* h1prev, const ushort_t* W1p,
    const float* b1p, float* c1, ushort_t* h1out)
{
    __shared__ __align__(16) float zs[4][16 * 68];
    float* zsw = zs[threadIdx.x >> 6];
    if (blockIdx.z == 0) {
        if (!(zmask & 1)) return;
        step_core<64, 32>(h1_for2, kU, 0, h2prev, W2p,
                          (const float4*)b2p, c2, h2out, zsw);
    } else {
        if (!(zmask & 2)) return;
        step_core<48, 16>(xbf, (long)kT * kD, (long)t1 * kD, h1prev, W1p,
                          (const float4*)b1p, c1, h1out, zsw);
    }
}

// out[b] = sigmoid(h[b,:] . Wfc + bfc), h in bf16
__global__ __launch_bounds__(256)
void fc_sigmoid(const ushort_t* __restrict__ h, const float* __restrict__ Wfc,
                const float* __restrict__ bfc, float* __restrict__ out)
{
    int b = blockIdx.x, tid = threadIdx.x;
    float s = 0.f;
    for (int j = tid; j < kU; j += 256) s += bf2f(h[(long)b * kU + j]) * Wfc[j];
    __shared__ float red[4];
    for (int off = 32; off > 0; off >>= 1) s += __shfl_down(s, off, 64);
    if ((tid & 63) == 0) red[tid >> 6] = s;
    __syncthreads();
    if (tid == 0) {
        float t = red[0] + red[1] + red[2] + red[3] + bfc[0];
        out[b] = 1.f / (1.f + expf(-t));
    }
}

extern "C" void kernel_launch(void* const* d_in, const int* in_sizes, int n_in,
                              void* d_out, int out_size, void* d_ws, size_t ws_size,
                              hipStream_t stream)
{
    (void)in_sizes; (void)n_in; (void)out_size; (void)ws_size;

    const int*   tokens = (const int*)d_in[0];
    const float* emb    = (const float*)d_in[1];
    const float* W1     = (const float*)d_in[2];
    const float* U1     = (const float*)d_in[3];
    const float* b1     = (const float*)d_in[4];
    const float* W2     = (const float*)d_in[5];
    const float* U2     = (const float*)d_in[6];
    const float* b2     = (const float*)d_in[7];
    const float* Wfc    = (const float*)d_in[8];
    const float* bfc    = (const float*)d_in[9];
    float* out = (float*)d_out;

    // Workspace: ~86 MB
    ushort_t* W1p = (ushort_t*)d_ws;                       // [1536*4096] bf16
    ushort_t* W2p = W1p + (size_t)1536 * kG;               // [2048*4096] bf16
    float* b1p = (float*)(W2p + (size_t)2048 * kG);        // [4096] f32
    float* b2p = b1p + kG;                                 // [4096] f32
    float* c1  = b2p + kG;                                 // [256*1024] f32
    float* c2  = c1 + (size_t)kB * kU;
    ushort_t* hbuf = (ushort_t*)(c2 + (size_t)kB * kU);    // 4 x [256*1024] bf16
    ushort_t* h1b[2] = { hbuf, hbuf + (size_t)kB * kU };
    ushort_t* h2b[2] = { hbuf + 2 * (size_t)kB * kU, hbuf + 3 * (size_t)kB * kU };
    ushort_t* xbf = hbuf + 4 * (size_t)kB * kU;            // [B*T*512] bf16

    repack_weights<<<48 * 64, 256, 0, stream>>>(W1, U1, 512, 1536, W1p);
    repack_weights<<<64 * 64, 256, 0, stream>>>(W2, U2, 1024, 2048, W2p);
    repack_bias<<<16, 256, 0, stream>>>(b1, b2, b1p, b2p);
    xgather<<<kB * kT, 128, 0, stream>>>(tokens, emb, xbf);
    // zero c1,c2 (fp32) + all h buffers (bf16): contiguous 4 MB
    hipMemsetAsync(c1, 0, (size_t)kB * kU * (2 * 4 + 4 * 2), stream);

    for (int l = 0; l <= kT; l++) {
        int t2 = l - 1, t1 = l;
        int zmask = (t2 >= 0 ? 1 : 0) | (t1 < kT ? 2 : 0);
        lstm_merged<<<dim3(32, 4, 2), 256, 0, stream>>>(zmask,
            h1b[(t2 + 1) & 1], h2b[t2 & 1], W2p, b2p, c2, h2b[(t2 + 1) & 1],
            xbf, t1, h1b[t1 & 1], W1p, b1p, c1, h1b[(t1 + 1) & 1]);
    }

    fc_sigmoid<<<kB, 256, 0, stream>>>(h2b[0], Wfc, bfc, out);
}